// Round 11
// baseline (500.702 us; speedup 1.0000x reference)
//
#include <hip/hip_runtime.h>

// ---------------------------------------------------------------------------
// AttentiveDensenet on MI355X (gfx950) — round 11: GEMM switched to
// mfma_f32_32x32x16_bf16 (17% fewer MFMA cycles) with k-chunk-major LDS
// ([chunk][row][8], conflict-free reads; linear gl_lds dest, row-strided
// per-lane global source). Epilogues use verified 32x32 C/D mapping.
// Everything else identical to round 10.
// B=8, C=256, H=W=32 (HW=1024), L=4, NH=8, K=V=64.
// ---------------------------------------------------------------------------

typedef __attribute__((ext_vector_type(8))) short short8;
typedef __attribute__((ext_vector_type(16))) float f32x16;
typedef __attribute__((ext_vector_type(2))) float f32x2;
typedef __attribute__((ext_vector_type(4))) unsigned short ushort4_t;
typedef __attribute__((ext_vector_type(4))) unsigned int uint4_t;

#define NTOK 65536   // B*HW*NH
#define NPIX 8192    // B*HW

// prep block layout: [0,7752) flat (kqv cast + bias + borders);
// [7752,8776) w1 rows; [8776,9800) w2 rows; [9800,9928) x->xacc/xcl
#define PREP_FLAT 7752
#define PREP_W1   (PREP_FLAT + 1024)
#define PREP_W2   (PREP_W1 + 1024)
#define PREP_TOT  (PREP_W2 + 128)

__device__ __forceinline__ float bf2f(unsigned short u) {
  unsigned int v = ((unsigned int)u) << 16;
  float f; __builtin_memcpy(&f, &v, 4); return f;
}
__device__ __forceinline__ unsigned short f2bf(float f) {
  unsigned int u; __builtin_memcpy(&u, &f, 4);
  u = (u + 0x7FFFu + ((u >> 16) & 1u)) >> 16;
  return (unsigned short)u;
}
__device__ __forceinline__ float blo(unsigned int u) {
  unsigned int v = u << 16; float f; __builtin_memcpy(&f, &v, 4); return f;
}
__device__ __forceinline__ float bhi(unsigned int u) {
  unsigned int v = u & 0xFFFF0000u; float f; __builtin_memcpy(&f, &v, 4); return f;
}

__device__ __forceinline__ void gl_lds16(const unsigned short* g, const unsigned short* l) {
  __builtin_amdgcn_global_load_lds(
      (const __attribute__((address_space(1))) unsigned int*)g,
      (__attribute__((address_space(3))) unsigned int*)l, 16, 0, 0);
}

// ---------------------------------------------------------------------------
// one-shot prep (unchanged from round 10)
// ---------------------------------------------------------------------------
__global__ void k_prep(const float* __restrict__ kw, const float* __restrict__ vw,
                       const float* __restrict__ qw, const float* __restrict__ ow1,
                       const float* __restrict__ ow2, const float* __restrict__ kb,
                       const float* __restrict__ vb, const float* __restrict__ qb,
                       unsigned short* __restrict__ wkqv, unsigned short* __restrict__ w1,
                       unsigned short* __restrict__ w2, float* __restrict__ biascat,
                       unsigned int* __restrict__ opad_u32, unsigned int* __restrict__ h1pad_u32,
                       const float* __restrict__ x_in, float* __restrict__ xacc,
                       unsigned short* __restrict__ xcl) {
  const int bid = blockIdx.x;
  const int tid = threadIdx.x;

  if (bid < PREP_FLAT) {
    long i = (long)bid * 256 + tid;
    if (i < 1572864) {
      int idx = (int)(i & 131071); int sl = (int)(i >> 17); int slot = sl % 3, l = sl / 3;
      const float* s = slot == 0 ? kw : slot == 1 ? vw : qw;
      float v = s[(size_t)l * 131072 + idx];
      if (slot == 2) v *= 0.125f;
      wkqv[i] = f2bf(v);
      return;
    }
    i -= 1572864;
    if (i < 6144) {
      int o = (int)(i & 511); int sl = (int)(i >> 9); int slot = sl % 3, l = sl / 3;
      const float* s = slot == 0 ? kb : slot == 1 ? vb : qb;
      float v = s[l * 512 + o];
      if (slot == 2) v *= 0.125f;
      biascat[i] = v;
      return;
    }
    i -= 6144;
    auto border_pix = [](int pidx) -> size_t {
      const int b = pidx / 132, t = pidx % 132;
      int y, x;
      if (t < 34) { y = 0; x = t; }
      else if (t < 68) { y = 33; x = t - 34; }
      else { const int j = t - 68; y = 1 + (j >> 1); x = (j & 1) * 33; }
      return (size_t)b * 1156 + y * 34 + x;
    };
    if (i < 270336) {
      const int pidx = (int)(i >> 8), c = (int)(i & 255);
      opad_u32[border_pix(pidx) * 256 + c] = 0u;
      return;
    }
    i -= 270336;
    if (i < 135168) {
      const int pidx = (int)(i >> 7), c = (int)(i & 127);
      h1pad_u32[border_pix(pidx) * 128 + c] = 0u;
    }
    return;
  }

  if (bid < PREP_W1) {
    __shared__ unsigned short lds[4608];
    const int m = bid - PREP_FLAT;
    const float* src = ow1 + (size_t)m * 4608;
    #pragma unroll
    for (int k = 0; k < 18; k++) lds[k * 256 + tid] = f2bf(src[k * 256 + tid]);
    __syncthreads();
    unsigned int* dst = (unsigned int*)(w1 + (size_t)m * 4608);
    #pragma unroll
    for (int j = 0; j < 9; j++) {
      const int u = j * 256 + tid;
      const int o = 2 * u;
      const int tap = o >> 9, c = o & 511;
      dst[u] = (unsigned int)lds[c * 9 + tap] |
               ((unsigned int)lds[(c + 1) * 9 + tap] << 16);
    }
    return;
  }

  if (bid < PREP_W2) {
    __shared__ unsigned short lds2[2304];
    const int m = bid - PREP_W1;
    const float* src = ow2 + (size_t)m * 2304;
    #pragma unroll
    for (int k = 0; k < 9; k++) lds2[k * 256 + tid] = f2bf(src[k * 256 + tid]);
    __syncthreads();
    unsigned int* dst = (unsigned int*)(w2 + (size_t)m * 2304);
    #pragma unroll
    for (int j = 0; j < 5; j++) {
      const int u = j * 256 + tid;
      if (u < 1152) {
        const int o = 2 * u;
        const int tap = o >> 8, c = o & 255;
        dst[u] = (unsigned int)lds2[c * 9 + tap] |
                 ((unsigned int)lds2[(c + 1) * 9 + tap] << 16);
      }
    }
    return;
  }

  // ---- x (f32 [B][256][1024]) -> xacc copy + xcl (bf16 [B][1024][256]) ----
  {
    __shared__ unsigned short t[64][68];
    const int xb = bid - PREP_W2;
    const int hw0 = (xb & 15) * 64, b = xb >> 4;
    for (int cc = 0; cc < 4; cc++) {
      __syncthreads();
      {
        const int px = tid & 63, c = tid >> 6;
        #pragma unroll
        for (int i = 0; i < 16; i++) {
          const size_t idx = ((size_t)b * 256 + cc * 64 + c + i * 4) * 1024 + hw0 + px;
          const float v = x_in[idx];
          xacc[idx] = v;
          t[px][c + i * 4] = f2bf(v);
        }
      }
      __syncthreads();
      {
        const int px = tid >> 2, c0 = (tid & 3) * 16;
        unsigned short* dp = xcl + ((size_t)b * 1024 + hw0 + px) * 256 + cc * 64 + c0;
        short8 v0, v1;
        #pragma unroll
        for (int i = 0; i < 8; i++) { v0[i] = (short)t[px][c0 + i]; v1[i] = (short)t[px][c0 + 8 + i]; }
        *(short8*)dp = v0; *(short8*)(dp + 8) = v1;
      }
    }
  }
}

// ---------------------------------------------------------------------------
// MFMA GEMM v4: 128x128 tile, 4 waves (2x2 of 64x64), K-step 64,
// mfma_f32_32x32x16_bf16 (2x2 frags of 32x32, 16 MFMA/K-step/wave).
// LDS k-chunk-major: [chunk 0..7][row 0..127][8 shorts] — reads conflict-free.
// Staging: linear LDS dest (gl_lds16), per-lane global source row-strided.
// NBUF=2: dbuf (convs, grid-limited). NBUF=1: single (QKV, 3 blocks/CU).
// ---------------------------------------------------------------------------
template<int MODE, int NSTEP, int KDIM, int CIN, int NBUF>
__global__ __launch_bounds__(256) void k_gemm(
    const unsigned short* __restrict__ W,
    const unsigned short* __restrict__ act,
    const float* __restrict__ bias,
    int l,
    unsigned short* __restrict__ ktok, unsigned short* __restrict__ vtok,
    unsigned short* __restrict__ qtok,
    unsigned short* __restrict__ pout) {
  __shared__ unsigned short sm[NBUF][2][8192];   // [buf][A/B][chunk][row][8]

  const int bid = blockIdx.x;
  int m0, b, pix0, s;
  if constexpr (MODE == 0) {
    const int xcd = bid & 7, li = bid >> 3;
    const int nt = xcd * 8 + (li & 7);
    m0 = (li >> 3) * 128; s = 0;
    b = nt >> 3; pix0 = (nt & 7) * 128;
  } else {
    const int xcd = bid & 7, li = bid >> 3;
    const int nt = xcd * 8 + (li & 7);
    const int r = li >> 3;
    m0 = (r & 1) * 128; s = r >> 1;
    b = nt >> 3; pix0 = (nt & 7) * 128;
  }
  constexpr int SW = (MODE == 1) ? 128 : 64;

  const int tid = threadIdx.x;
  const int wid = tid >> 6, lane = tid & 63;
  const int l31 = lane & 31, hi = lane >> 5;
  const int m_off = (wid >> 1) * 64, n_off = (wid & 1) * 64;

  // staging: op (wid,j) fills LDS slots u = (wid*4+j)*64 + lane
  //   chunk = (wid*4+j)>>1 (uniform per op), row = ((wid*4+j)&1)*64 + lane
  const unsigned short* gA[4];
  const unsigned short* gB[4];
  #pragma unroll
  for (int j = 0; j < 4; j++) {
    const int idx = wid * 4 + j;
    const int chunk = idx >> 1;
    const int row = (idx & 1) * 64 + lane;
    gA[j] = W + (size_t)(m0 + row) * KDIM + (MODE ? s * SW : 0) + chunk * 8;
    if constexpr (MODE == 0) {
      gB[j] = act + ((size_t)b * 1024 + pix0 + row) * 256 + chunk * 8;
    } else {
      const int pix = pix0 + row, py = pix >> 5, px = pix & 31;
      gB[j] = act + (size_t)b * 1156 * CIN + ((size_t)py * 34 + px) * CIN + s * SW + chunk * 8;
    }
  }

  auto offA = [&](int st) -> int {
    if constexpr (MODE == 0) return st * 64;
    else if constexpr (MODE == 1) return (st >> 1) * 512 + (st & 1) * 64;
    else return st * 256;
  };
  auto offB = [&](int st) -> int {
    if constexpr (MODE == 0) return st * 64;
    else if constexpr (MODE == 1) {
      const int tap = st >> 1, dy = tap / 3, dx = tap - dy * 3;
      return (dy * 34 + dx) * 512 + (st & 1) * 64;
    } else {
      const int dy = st / 3, dx = st - dy * 3;
      return (dy * 34 + dx) * 256;
    }
  };
  auto STAGE = [&](int bf, int st) {
    const int oa = offA(st), ob = offB(st);
    #pragma unroll
    for (int j = 0; j < 4; j++) gl_lds16(gA[j] + oa, &sm[bf][0][(wid * 4 + j) * 512]);
    #pragma unroll
    for (int j = 0; j < 4; j++) gl_lds16(gB[j] + ob, &sm[bf][1][(wid * 4 + j) * 512]);
  };

  // read bases: frag f row-addr (shorts); chunk (ks*2+hi) added per ks
  const int ard0 = (m_off + l31) * 8,      ard1 = (m_off + 32 + l31) * 8;
  const int brd0 = (n_off + l31) * 8,      brd1 = (n_off + 32 + l31) * 8;

  f32x16 acc[2][2] = {};

  auto COMPUTE = [&](int cur) {
    #pragma unroll
    for (int ks = 0; ks < 4; ks++) {
      const int co = (ks * 2 + hi) * 1024;
      short8 a0 = *(const short8*)&sm[cur][0][co + ard0];
      short8 a1 = *(const short8*)&sm[cur][0][co + ard1];
      short8 b0 = *(const short8*)&sm[cur][1][co + brd0];
      short8 b1 = *(const short8*)&sm[cur][1][co + brd1];
      acc[0][0] = __builtin_amdgcn_mfma_f32_32x32x16_bf16(a0, b0, acc[0][0], 0, 0, 0);
      acc[0][1] = __builtin_amdgcn_mfma_f32_32x32x16_bf16(a0, b1, acc[0][1], 0, 0, 0);
      acc[1][0] = __builtin_amdgcn_mfma_f32_32x32x16_bf16(a1, b0, acc[1][0], 0, 0, 0);
      acc[1][1] = __builtin_amdgcn_mfma_f32_32x32x16_bf16(a1, b1, acc[1][1], 0, 0, 0);
    }
  };

  if constexpr (NBUF == 2) {
    STAGE(0, 0);
    __syncthreads();
    #pragma unroll
    for (int st = 0; st < NSTEP; st++) {
      if (st + 1 < NSTEP) STAGE((st + 1) & 1, st + 1);
      COMPUTE(st & 1);
      __syncthreads();
    }
  } else {
    #pragma unroll
    for (int st = 0; st < NSTEP; st++) {
      if (st) __syncthreads();
      STAGE(0, st);
      __syncthreads();
      COMPUTE(0);
    }
  }

  // D mapping (32x32): col = lane&31, row = (reg&3) + 8*(reg>>2) + 4*(lane>>5)
  if constexpr (MODE == 0) {
    #pragma unroll
    for (int mi = 0; mi < 2; mi++) {
      const int mbase = m0 + m_off + mi * 32;           // 32-aligned
      const int tensor = mbase >> 9, head = (mbase >> 6) & 7, d0b = mbase & 63;
      unsigned short* dst = (tensor == 0) ? ktok + (size_t)l * NTOK * 64
                          : (tensor == 1) ? vtok + (size_t)l * NTOK * 64 : qtok;
      #pragma unroll
      for (int ni = 0; ni < 2; ni++) {
        const int n = pix0 + n_off + ni * 32 + l31;
        unsigned short* tokp = dst + (((size_t)b * 1024 + n) * 8 + head) * 64;
        #pragma unroll
        for (int q = 0; q < 4; q++) {
          const int rowoff = 8 * q + 4 * hi;
          const int m4 = mbase + rowoff;
          ushort4_t pk;
          #pragma unroll
          for (int e = 0; e < 4; e++) pk[e] = f2bf(acc[mi][ni][q * 4 + e] + bias[m4 + e]);
          *(ushort4_t*)&tokp[d0b + rowoff] = pk;
        }
      }
    }
  } else {
    // bf16 partials [s*256 + c][8192]
    #pragma unroll
    for (int mi = 0; mi < 2; mi++) {
      const int mbase = m0 + m_off + mi * 32;
      #pragma unroll
      for (int ni = 0; ni < 2; ni++) {
        const int n = n_off + ni * 32 + l31;
        #pragma unroll
        for (int q = 0; q < 4; q++) {
          const int rowoff = 8 * q + 4 * hi;
          unsigned short* orow = pout + (size_t)(s * 256 + mbase + rowoff) * 8192
                               + (size_t)b * 1024 + pix0 + n;
          #pragma unroll
          for (int e = 0; e < 4; e++) orow[(size_t)e * 8192] = f2bf(acc[mi][ni][q * 4 + e]);
        }
      }
    }
  }
}

// ---------------------------------------------------------------------------
// attention: 4 lanes/token, 16 tokens/wave (unchanged)
// ---------------------------------------------------------------------------
template<int L>
__global__ __launch_bounds__(256) void k_attn(const unsigned int* __restrict__ q_tok,
                                              const unsigned int* __restrict__ k_tok,
                                              const unsigned int* __restrict__ v_tok,
                                              unsigned int* __restrict__ opad) {
  constexpr int T = L + 2;
  const int lane = threadIdx.x & 63, wid = threadIdx.x >> 6;
  const int ti = lane >> 2, dq = lane & 3;
  const int token = blockIdx.x * 64 + wid * 16 + ti;
  const size_t rowq = (size_t)token * 32 + dq * 8;

  unsigned int q[8];
  *(uint4_t*)&q[0] = *(const uint4_t*)(q_tok + rowq);
  *(uint4_t*)&q[4] = *(const uint4_t*)(q_tok + rowq + 4);
  float qf[16];
  #pragma unroll
  for (int j = 0; j < 8; j++) {
    qf[2 * j]     = blo(q[j]);
    qf[2 * j + 1] = bhi(q[j]);
  }

  float s[T];
  s[T - 1] = 0.0f;
  #pragma unroll
  for (int t = 0; t <= L; t++) {
    const unsigned int* kp = k_tok + (size_t)t * (NTOK * 32) + rowq;
    unsigned int kk[8];
    *(uint4_t*)&kk[0] = *(const uint4_t*)kp;
    *(uint4_t*)&kk[4] = *(const uint4_t*)(kp + 4);
    float p = 0.0f;
    #pragma unroll
    for (int j = 0; j < 8; j++) {
      p = fmaf(qf[2 * j], blo(kk[j]), p);
      p = fmaf(qf[2 * j + 1], bhi(kk[j]), p);
    }
    p += __shfl_xor(p, 1);
    p += __shfl_xor(p, 2);
    s[t] = p;
  }

  float mx = s[0];
  #pragma unroll
  for (int t = 1; t < T; t++) mx = fmaxf(mx, s[t]);
  float attn[T], sum = 0.0f;
  #pragma unroll
  for (int t = 0; t < T; t++) { attn[t] = __expf(s[t] - mx); sum += attn[t]; }
  const float inv = 1.0f / sum;
  #pragma unroll
  for (int t = 0; t < T; t++) attn[t] *= inv;

  if constexpr (T == 5) {
    float m1 = attn[0], m2 = 1e30f;
    #pragma unroll
    for (int t = 1; t < 5; t++) {
      const float a = attn[t];
      const float nm1 = fminf(m1, a);
      m2 = fminf(m2, fmaxf(m1, a));
      m1 = nm1;
    }
    const float delta = m2 + 1e-7f;
    float ws = 0.0f;
    #pragma unroll
    for (int t = 0; t < 5; t++) { attn[t] = fmaxf(attn[t] - delta, 0.0f); ws += attn[t]; }
    const float r = 1.0f / (ws + 1e-7f);
    #pragma unroll
    for (int t = 0; t < 5; t++) attn[t] *= r;
  }

  float o[16];
  #pragma unroll
  for (int i = 0; i < 16; i++) o[i] = 0.0f;
  #pragma unroll
  for (int t = 0; t <= L; t++) {
    const unsigned int* vp = v_tok + (size_t)t * (NTOK * 32) + rowq;
    unsigned int vv[8];
    *(uint4_t*)&vv[0] = *(const uint4_t*)vp;
    *(uint4_t*)&vv[4] = *(const uint4_t*)(vp + 4);
    const float a = attn[t];
    #pragma unroll
    for (int j = 0; j < 8; j++) {
      o[2 * j]     = fmaf(a, blo(vv[j]), o[2 * j]);
      o[2 * j + 1] = fmaf(a, bhi(vv[j]), o[2 * j + 1]);
    }
  }

  unsigned int po[8];
  #pragma unroll
  for (int j = 0; j < 8; j++) {
    unsigned int r;
    asm("v_cvt_pk_bf16_f32 %0, %1, %2" : "=v"(r) : "v"(o[2 * j]), "v"(o[2 * j + 1]));
    po[j] = r;
  }
  const int head = token & 7, pix = token >> 3;
  const int b = pix >> 10, hw = pix & 1023, y = hw >> 5, x = hw & 31;
  unsigned int* dp = opad +
      (((size_t)b * 1156 + (y + 1) * 34 + (x + 1)) * 512 + head * 64 + dq * 16) / 2;
  *(uint4_t*)dp = *(uint4_t*)&po[0];
  *(uint4_t*)(dp + 4) = *(uint4_t*)&po[4];
}

// ---------------------------------------------------------------------------
// conv1 BN stats: v = sum of 4 bf16 partials + bias (same expr as bn_relu_pad)
// ---------------------------------------------------------------------------
__global__ __launch_bounds__(512) void k_comb_stats(const unsigned int* __restrict__ p,
    const float* __restrict__ bias1, const float* __restrict__ g, const float* __restrict__ bta,
    float* __restrict__ stats) {
  const int c = blockIdx.x, tid = threadIdx.x;
  const float bs = bias1[c];
  const unsigned int* P0 = p + (size_t)c * 4096;
  float s = 0.0f, ss = 0.0f;
  #pragma unroll
  for (int k2 = 0; k2 < 2; k2++) {
    const int j = (k2 * 512 + tid) * 4;
    uint4_t a0 = *(const uint4_t*)(P0 + j);
    uint4_t a1 = *(const uint4_t*)(P0 + 1048576 + j);
    uint4_t a2 = *(const uint4_t*)(P0 + 2097152 + j);
    uint4_t a3 = *(const uint4_t*)(P0 + 3145728 + j);
    #pragma unroll
    for (int e = 0; e < 4; e++) {
      const float vl = blo(a0[e]) + blo(a1[e]) + blo(a2[e]) + blo(a3[e]) + bs;
      const float vh = bhi(a0[e]) + bhi(a1[e]) + bhi(a2[e]) + bhi(a3[e]) + bs;
      s += vl + vh; ss += vl * vl + vh * vh;
    }
  }
  #pragma unroll
  for (int o2 = 32; o2 > 0; o2 >>= 1) { s += __shfl_xor(s, o2); ss += __shfl_xor(ss, o2); }
  __shared__ float rs[8], rss[8];
  const int wid = tid >> 6, lane = tid & 63;
  if (lane == 0) { rs[wid] = s; rss[wid] = ss; }
  __syncthreads();
  if (tid == 0) {
    float S = 0.0f, SS = 0.0f;
    #pragma unroll
    for (int w = 0; w < 8; w++) { S += rs[w]; SS += rss[w]; }
    const float m = S * (1.0f / 8192.0f);
    const float var = SS * (1.0f / 8192.0f) - m * m;
    const float A = g[c] * rsqrtf(var + 1e-5f);
    stats[c] = A;
    stats[256 + c] = bta[c] - m * A;
  }
}

// ---------------------------------------------------------------------------
// re-sum partials + bias + BN + ReLU + transpose -> padded channel-last h1pad
// ---------------------------------------------------------------------------
__global__ __launch_bounds__(512) void k_bn_relu_pad(const unsigned int* __restrict__ p,
    const float* __restrict__ bias1, const float* __restrict__ stats,
    unsigned short* __restrict__ hpad) {
  __shared__ unsigned short t[32][264];
  const int hw0 = blockIdx.x * 32, b = blockIdx.y, tid = threadIdx.x;
  const int u = tid & 15, cg = tid >> 4;
  const int base = ((b * 1024 + hw0) >> 1);
  #pragma unroll
  for (int i = 0; i < 8; i++) {
    const int ch = i * 32 + cg;
    const float bs = bias1[ch];
    const float A = stats[ch], Bt = stats[256 + ch];
    const size_t j = (size_t)ch * 4096 + base + u;
    const unsigned int a0 = p[j];
    const unsigned int a1 = p[j + 1048576];
    const unsigned int a2 = p[j + 2097152];
    const unsigned int a3 = p[j + 3145728];
    const float vl = blo(a0) + blo(a1) + blo(a2) + blo(a3) + bs;
    const float vh = bhi(a0) + bhi(a1) + bhi(a2) + bhi(a3) + bs;
    t[2 * u][ch]     = f2bf(fmaxf(vl * A + Bt, 0.0f));
    t[2 * u + 1][ch] = f2bf(fmaxf(vh * A + Bt, 0.0f));
  }
  __syncthreads();
  const int px = tid >> 4, c0 = (tid & 15) * 16;
  const int y = hw0 >> 5, x = hw0 & 31;
  unsigned short* dp = hpad + ((size_t)b * 1156 + (y + 1) * 34 + (x + px + 1)) * 256 + c0;
  short8 v0, v1;
  #pragma unroll
  for (int i = 0; i < 8; i++) { v0[i] = (short)t[px][c0 + i]; v1[i] = (short)t[px][c0 + 8 + i]; }
  *(short8*)dp = v0; *(short8*)(dp + 8) = v1;
}

// ---------------------------------------------------------------------------
// conv2 combine: xacc += gamma * (sum of 4 bf16 partials + bias); refresh xcl
// ---------------------------------------------------------------------------
__global__ __launch_bounds__(512) void k_comb2(const unsigned int* __restrict__ p,
    const float* __restrict__ bias2, const float* __restrict__ gamma_p, int last,
    float* __restrict__ xacc, unsigned short* __restrict__ xcl) {
  __shared__ unsigned short t[32][264];
  const int hw0 = blockIdx.x * 32, b = blockIdx.y, tid = threadIdx.x;
  const int u = tid & 15, cg = tid >> 4;
  const float gmm = gamma_p[0];
  const int base = ((b * 1024 + hw0) >> 1);
  #pragma unroll
  for (int i = 0; i < 8; i++) {
    const int ch = i * 32 + cg;
    const float bs = bias2[ch];
    const size_t j = (size_t)ch * 4096 + base + u;
    const unsigned int a0 = p[j];
    const unsigned int a1 = p[j + 1048576];
    const unsigned int a2 = p[j + 2097152];
    const unsigned int a3 = p[j + 3145728];
    const float vl = blo(a0) + blo(a1) + blo(a2) + blo(a3) + bs;
    const float vh = bhi(a0) + bhi(a1) + bhi(a2) + bhi(a3) + bs;
    float* X = xacc + ((size_t)b * 256 + ch) * 1024 + hw0 + 2 * u;
    f32x2 xv = *(const f32x2*)X;
    const float xl = xv[0] + gmm * vl;
    const float xh = xv[1] + gmm * vh;
    f32x2 xw = {xl, xh};
    *(f32x2*)X = xw;
    t[2 * u][ch]     = f2bf(xl);
    t[2 * u + 1][ch] = f2bf(xh);
  }
  __syncthreads();
  if (!last) {
    const int px = tid >> 4, c0 = (tid & 15) * 16;
    unsigned short* dp = xcl + ((size_t)b * 1024 + hw0 + px) * 256 + c0;
    short8 v0, v1;
    #pragma unroll
    for (int i = 0; i < 8; i++) { v0[i] = (short)t[px][c0 + i]; v1[i] = (short)t[px][c0 + 8 + i]; }
    *(short8*)dp = v0; *(short8*)(dp + 8) = v1;
  }
}

// ---------------------------------------------------------------------------
extern "C" void kernel_launch(void* const* d_in, const int* in_sizes, int n_in,
                              void* d_out, int out_size, void* d_ws, size_t ws_size,
                              hipStream_t stream) {
  (void)in_sizes; (void)n_in; (void)out_size;
  const float* x_in   = (const float*)d_in[0];
  const float* kw     = (const float*)d_in[1];
  const float* kb     = (const float*)d_in[2];
  const float* qw     = (const float*)d_in[3];
  const float* qb     = (const float*)d_in[4];
  const float* vw     = (const float*)d_in[5];
  const float* vb     = (const float*)d_in[6];
  const float* ow1    = (const float*)d_in[7];
  const float* ob1    = (const float*)d_in[8];
  const float* bn_g   = (const float*)d_in[9];
  const float* bn_b   = (const float*)d_in[10];
  const float* ow2    = (const float*)d_in[11];
  const float* ob2    = (const float*)d_in[12];
  const float* gammas = (const float*)d_in[13];

  char* ws = (char*)d_ws;
  size_t off = 0;
  auto alloc = [&](size_t bytes) -> void* {
    void* pp = ws + off;
    off += (bytes + 255) & ~(size_t)255;
    return pp;
  };
  unsigned short* xcl     = (unsigned short*)alloc((size_t)NPIX * 256 * 2);
  unsigned short* k_tok   = (unsigned short*)alloc((size_t)4 * NTOK * 64 * 2);
  unsigned short* v_tok   = (unsigned short*)alloc((size_t)4 * NTOK * 64 * 2);
  unsigned short* q_tok   = (unsigned short*)alloc((size_t)NTOK * 64 * 2);
  unsigned short* opad    = (unsigned short*)alloc((size_t)8 * 1156 * 512 * 2);
  unsigned short* h1pad   = (unsigned short*)alloc((size_t)8 * 1156 * 256 * 2);
  unsigned short* p1      = (unsigned short*)alloc((size_t)4 * 256 * 8192 * 2);
  float*          stats   = (float*)alloc(512 * 4);
  unsigned short* wkqv    = (unsigned short*)alloc((size_t)4 * 3 * 512 * 256 * 2);
  unsigned short* w1bf    = (unsigned short*)alloc((size_t)1024 * 4608 * 2);
  unsigned short* w2bf    = (unsigned short*)alloc((size_t)1024 * 2304 * 2);
  float*          biascat = (float*)alloc((size_t)6144 * 4);
  if (off > ws_size) return;

  float* xacc = (float*)d_out;

  k_prep<<<PREP_TOT, 256, 0, stream>>>(
      kw, vw, qw, ow1, ow2, kb, vb, qb,
      wkqv, w1bf, w2bf, biascat,
      (unsigned int*)opad, (unsigned int*)h1pad,
      x_in, xacc, xcl);

  for (int l = 0; l < 4; l++) {
    k_gemm<0, 4, 256, 256, 1><<<768, 256, 0, stream>>>(
        wkqv + (size_t)l * 3 * 512 * 256, xcl, biascat + l * 1536, l,
        k_tok, v_tok, q_tok, nullptr);
    const unsigned int* qt = (const unsigned int*)q_tok;
    const unsigned int* kt = (const unsigned int*)k_tok;
    const unsigned int* vt = (const unsigned int*)v_tok;
    unsigned int* op = (unsigned int*)opad;
    switch (l) {
      case 0: k_attn<0><<<1024, 256, 0, stream>>>(qt, kt, vt, op); break;
      case 1: k_attn<1><<<1024, 256, 0, stream>>>(qt, kt, vt, op); break;
      case 2: k_attn<2><<<1024, 256, 0, stream>>>(qt, kt, vt, op); break;
      default: k_attn<3><<<1024, 256, 0, stream>>>(qt, kt, vt, op); break;
    }
    k_gemm<1, 18, 4608, 512, 2><<<512, 256, 0, stream>>>(
        w1bf + (size_t)l * 256 * 4608, opad, nullptr, l,
        nullptr, nullptr, nullptr, p1);
    k_comb_stats<<<256, 512, 0, stream>>>((const unsigned int*)p1, ob1 + l * 256,
                                          bn_g + l * 256, bn_b + l * 256, stats);
    k_bn_relu_pad<<<dim3(32, 8), 512, 0, stream>>>((const unsigned int*)p1,
                                                   ob1 + l * 256, stats, h1pad);
    k_gemm<2, 9, 2304, 256, 2><<<512, 256, 0, stream>>>(
        w2bf + (size_t)l * 256 * 2304, h1pad, nullptr, l,
        nullptr, nullptr, nullptr, p1);
    k_comb2<<<dim3(32, 8), 512, 0, stream>>>((const unsigned int*)p1, ob2 + l * 256,
                                             gammas + l, (l == 3) ? 1 : 0, xacc, xcl);
  }
}

// Round 12
// 371.989 us; speedup vs baseline: 1.3460x; 1.3460x over previous
//
#include <hip/hip_runtime.h>

// ---------------------------------------------------------------------------
// AttentiveDensenet on MI355X (gfx950) — round 12: round-10 staging (row-major
// XOR-swizzled LDS, coalesced global_load_lds) + 32x32x16 MFMA fragment reads
// (validated C/D map from round 11). Only COMPUTE + epilogue differ from r10.
// B=8, C=256, H=W=32 (HW=1024), L=4, NH=8, K=V=64.
// ---------------------------------------------------------------------------

typedef __attribute__((ext_vector_type(8))) short short8;
typedef __attribute__((ext_vector_type(16))) float f32x16;
typedef __attribute__((ext_vector_type(2))) float f32x2;
typedef __attribute__((ext_vector_type(4))) unsigned short ushort4_t;
typedef __attribute__((ext_vector_type(4))) unsigned int uint4_t;

#define NTOK 65536   // B*HW*NH
#define NPIX 8192    // B*HW

#define PREP_FLAT 7752
#define PREP_W1   (PREP_FLAT + 1024)
#define PREP_W2   (PREP_W1 + 1024)
#define PREP_TOT  (PREP_W2 + 128)

__device__ __forceinline__ float bf2f(unsigned short u) {
  unsigned int v = ((unsigned int)u) << 16;
  float f; __builtin_memcpy(&f, &v, 4); return f;
}
__device__ __forceinline__ unsigned short f2bf(float f) {
  unsigned int u; __builtin_memcpy(&u, &f, 4);
  u = (u + 0x7FFFu + ((u >> 16) & 1u)) >> 16;
  return (unsigned short)u;
}
__device__ __forceinline__ float blo(unsigned int u) {
  unsigned int v = u << 16; float f; __builtin_memcpy(&f, &v, 4); return f;
}
__device__ __forceinline__ float bhi(unsigned int u) {
  unsigned int v = u & 0xFFFF0000u; float f; __builtin_memcpy(&f, &v, 4); return f;
}

__device__ __forceinline__ void gl_lds16(const unsigned short* g, const unsigned short* l) {
  __builtin_amdgcn_global_load_lds(
      (const __attribute__((address_space(1))) unsigned int*)g,
      (__attribute__((address_space(3))) unsigned int*)l, 16, 0, 0);
}

// ---------------------------------------------------------------------------
// one-shot prep (identical to round 10)
// ---------------------------------------------------------------------------
__global__ void k_prep(const float* __restrict__ kw, const float* __restrict__ vw,
                       const float* __restrict__ qw, const float* __restrict__ ow1,
                       const float* __restrict__ ow2, const float* __restrict__ kb,
                       const float* __restrict__ vb, const float* __restrict__ qb,
                       unsigned short* __restrict__ wkqv, unsigned short* __restrict__ w1,
                       unsigned short* __restrict__ w2, float* __restrict__ biascat,
                       unsigned int* __restrict__ opad_u32, unsigned int* __restrict__ h1pad_u32,
                       const float* __restrict__ x_in, float* __restrict__ xacc,
                       unsigned short* __restrict__ xcl) {
  const int bid = blockIdx.x;
  const int tid = threadIdx.x;

  if (bid < PREP_FLAT) {
    long i = (long)bid * 256 + tid;
    if (i < 1572864) {
      int idx = (int)(i & 131071); int sl = (int)(i >> 17); int slot = sl % 3, l = sl / 3;
      const float* s = slot == 0 ? kw : slot == 1 ? vw : qw;
      float v = s[(size_t)l * 131072 + idx];
      if (slot == 2) v *= 0.125f;
      wkqv[i] = f2bf(v);
      return;
    }
    i -= 1572864;
    if (i < 6144) {
      int o = (int)(i & 511); int sl = (int)(i >> 9); int slot = sl % 3, l = sl / 3;
      const float* s = slot == 0 ? kb : slot == 1 ? vb : qb;
      float v = s[l * 512 + o];
      if (slot == 2) v *= 0.125f;
      biascat[i] = v;
      return;
    }
    i -= 6144;
    auto border_pix = [](int pidx) -> size_t {
      const int b = pidx / 132, t = pidx % 132;
      int y, x;
      if (t < 34) { y = 0; x = t; }
      else if (t < 68) { y = 33; x = t - 34; }
      else { const int j = t - 68; y = 1 + (j >> 1); x = (j & 1) * 33; }
      return (size_t)b * 1156 + y * 34 + x;
    };
    if (i < 270336) {
      const int pidx = (int)(i >> 8), c = (int)(i & 255);
      opad_u32[border_pix(pidx) * 256 + c] = 0u;
      return;
    }
    i -= 270336;
    if (i < 135168) {
      const int pidx = (int)(i >> 7), c = (int)(i & 127);
      h1pad_u32[border_pix(pidx) * 128 + c] = 0u;
    }
    return;
  }

  if (bid < PREP_W1) {
    __shared__ unsigned short lds[4608];
    const int m = bid - PREP_FLAT;
    const float* src = ow1 + (size_t)m * 4608;
    #pragma unroll
    for (int k = 0; k < 18; k++) lds[k * 256 + tid] = f2bf(src[k * 256 + tid]);
    __syncthreads();
    unsigned int* dst = (unsigned int*)(w1 + (size_t)m * 4608);
    #pragma unroll
    for (int j = 0; j < 9; j++) {
      const int u = j * 256 + tid;
      const int o = 2 * u;
      const int tap = o >> 9, c = o & 511;
      dst[u] = (unsigned int)lds[c * 9 + tap] |
               ((unsigned int)lds[(c + 1) * 9 + tap] << 16);
    }
    return;
  }

  if (bid < PREP_W2) {
    __shared__ unsigned short lds2[2304];
    const int m = bid - PREP_W1;
    const float* src = ow2 + (size_t)m * 2304;
    #pragma unroll
    for (int k = 0; k < 9; k++) lds2[k * 256 + tid] = f2bf(src[k * 256 + tid]);
    __syncthreads();
    unsigned int* dst = (unsigned int*)(w2 + (size_t)m * 2304);
    #pragma unroll
    for (int j = 0; j < 5; j++) {
      const int u = j * 256 + tid;
      if (u < 1152) {
        const int o = 2 * u;
        const int tap = o >> 8, c = o & 255;
        dst[u] = (unsigned int)lds2[c * 9 + tap] |
                 ((unsigned int)lds2[(c + 1) * 9 + tap] << 16);
      }
    }
    return;
  }

  // ---- x (f32 [B][256][1024]) -> xacc copy + xcl (bf16 [B][1024][256]) ----
  {
    __shared__ unsigned short t[64][68];
    const int xb = bid - PREP_W2;
    const int hw0 = (xb & 15) * 64, b = xb >> 4;
    for (int cc = 0; cc < 4; cc++) {
      __syncthreads();
      {
        const int px = tid & 63, c = tid >> 6;
        #pragma unroll
        for (int i = 0; i < 16; i++) {
          const size_t idx = ((size_t)b * 256 + cc * 64 + c + i * 4) * 1024 + hw0 + px;
          const float v = x_in[idx];
          xacc[idx] = v;
          t[px][c + i * 4] = f2bf(v);
        }
      }
      __syncthreads();
      {
        const int px = tid >> 2, c0 = (tid & 3) * 16;
        unsigned short* dp = xcl + ((size_t)b * 1024 + hw0 + px) * 256 + cc * 64 + c0;
        short8 v0, v1;
        #pragma unroll
        for (int i = 0; i < 8; i++) { v0[i] = (short)t[px][c0 + i]; v1[i] = (short)t[px][c0 + 8 + i]; }
        *(short8*)dp = v0; *(short8*)(dp + 8) = v1;
      }
    }
  }
}

// ---------------------------------------------------------------------------
// MFMA GEMM v5: 128x128 tile, 4 waves (2x2 of 64x64), K-step 64,
// STAGING identical to round 10 (row-major LDS, chunk ^= row&7 XOR swizzle,
// coalesced 8x128B global pattern via pre-swizzled per-lane source).
// COMPUTE: mfma_f32_32x32x16_bf16, 2x2 frags, 16 MFMA/K-step/wave; fragment
// reads use the same swizzle lookup at 32-row granularity.
// NBUF=2: dbuf (convs). NBUF=1: single (QKV).
// MODE 0: QKV dense K=256; MODE 1: conv1 CIN=512 split-4; MODE 2: conv2.
// ---------------------------------------------------------------------------
template<int MODE, int NSTEP, int KDIM, int CIN, int NBUF>
__global__ __launch_bounds__(256) void k_gemm(
    const unsigned short* __restrict__ W,
    const unsigned short* __restrict__ act,
    const float* __restrict__ bias,
    int l,
    unsigned short* __restrict__ ktok, unsigned short* __restrict__ vtok,
    unsigned short* __restrict__ qtok,
    unsigned short* __restrict__ pout) {
  __shared__ unsigned short sm[NBUF][2][8192];   // [buf][A/B][128 rows x 64 k]

  const int bid = blockIdx.x;
  int m0, b, pix0, s;
  if constexpr (MODE == 0) {
    const int xcd = bid & 7, li = bid >> 3;
    const int nt = xcd * 8 + (li & 7);
    m0 = (li >> 3) * 128; s = 0;
    b = nt >> 3; pix0 = (nt & 7) * 128;
  } else {
    const int xcd = bid & 7, li = bid >> 3;
    const int nt = xcd * 8 + (li & 7);
    const int r = li >> 3;
    m0 = (r & 1) * 128; s = r >> 1;
    b = nt >> 3; pix0 = (nt & 7) * 128;
  }
  constexpr int SW = (MODE == 1) ? 128 : 64;

  const int tid = threadIdx.x;
  const int wid = tid >> 6, lane = tid & 63;
  const int l31 = lane & 31, hi = lane >> 5;
  const int m_off = (wid >> 1) * 64, n_off = (wid & 1) * 64;

  // staging (round-10): per-lane pre-swizzled global source, linear LDS dest
  const unsigned short* gA[4];
  const unsigned short* gB[4];
  #pragma unroll
  for (int j = 0; j < 4; j++) {
    const int o = (wid * 4 + j) * 512 + lane * 8;
    const int row = o >> 6;
    const int ksw = (((o >> 3) & 7) ^ (row & 7)) * 8;
    gA[j] = W + (size_t)(m0 + row) * KDIM + (MODE ? s * SW : 0) + ksw;
    if constexpr (MODE == 0) {
      gB[j] = act + ((size_t)b * 1024 + pix0 + row) * 256 + ksw;
    } else {
      const int pix = pix0 + row, py = pix >> 5, px = pix & 31;
      gB[j] = act + (size_t)b * 1156 * CIN + ((size_t)py * 34 + px) * CIN + s * SW + ksw;
    }
  }

  auto offA = [&](int st) -> int {
    if constexpr (MODE == 0) return st * 64;
    else if constexpr (MODE == 1) return (st >> 1) * 512 + (st & 1) * 64;
    else return st * 256;
  };
  auto offB = [&](int st) -> int {
    if constexpr (MODE == 0) return st * 64;
    else if constexpr (MODE == 1) {
      const int tap = st >> 1, dy = tap / 3, dx = tap - dy * 3;
      return (dy * 34 + dx) * 512 + (st & 1) * 64;
    } else {
      const int dy = st / 3, dx = st - dy * 3;
      return (dy * 34 + dx) * 256;
    }
  };
  auto STAGE = [&](int bf, int st) {
    const int oa = offA(st), ob = offB(st);
    #pragma unroll
    for (int j = 0; j < 4; j++) gl_lds16(gA[j] + oa, &sm[bf][0][(wid * 4 + j) * 512]);
    #pragma unroll
    for (int j = 0; j < 4; j++) gl_lds16(gB[j] + ob, &sm[bf][1][(wid * 4 + j) * 512]);
  };

  // fragment row addresses (swizzle applied per-ks below)
  const int ra0 = m_off + l31, ra1 = m_off + 32 + l31;
  const int rb0 = n_off + l31, rb1 = n_off + 32 + l31;

  f32x16 acc[2][2] = {};

  auto COMPUTE = [&](int cur) {
    #pragma unroll
    for (int ks = 0; ks < 4; ks++) {
      const int ch = ks * 2 + hi;                       // 8-k chunk index
      short8 a0 = *(const short8*)&sm[cur][0][ra0 * 64 + ((ch ^ (ra0 & 7)) * 8)];
      short8 a1 = *(const short8*)&sm[cur][0][ra1 * 64 + ((ch ^ (ra1 & 7)) * 8)];
      short8 b0 = *(const short8*)&sm[cur][1][rb0 * 64 + ((ch ^ (rb0 & 7)) * 8)];
      short8 b1 = *(const short8*)&sm[cur][1][rb1 * 64 + ((ch ^ (rb1 & 7)) * 8)];
      acc[0][0] = __builtin_amdgcn_mfma_f32_32x32x16_bf16(a0, b0, acc[0][0], 0, 0, 0);
      acc[0][1] = __builtin_amdgcn_mfma_f32_32x32x16_bf16(a0, b1, acc[0][1], 0, 0, 0);
      acc[1][0] = __builtin_amdgcn_mfma_f32_32x32x16_bf16(a1, b0, acc[1][0], 0, 0, 0);
      acc[1][1] = __builtin_amdgcn_mfma_f32_32x32x16_bf16(a1, b1, acc[1][1], 0, 0, 0);
    }
  };

  if constexpr (NBUF == 2) {
    STAGE(0, 0);
    __syncthreads();
    #pragma unroll
    for (int st = 0; st < NSTEP; st++) {
      if (st + 1 < NSTEP) STAGE((st + 1) & 1, st + 1);
      COMPUTE(st & 1);
      __syncthreads();
    }
  } else {
    #pragma unroll
    for (int st = 0; st < NSTEP; st++) {
      if (st) __syncthreads();
      STAGE(0, st);
      __syncthreads();
      COMPUTE(0);
    }
  }

  // D mapping (32x32, HW-verified): col = lane&31, row = (reg&3)+8*(reg>>2)+4*hi
  if constexpr (MODE == 0) {
    #pragma unroll
    for (int mi = 0; mi < 2; mi++) {
      const int mbase = m0 + m_off + mi * 32;
      const int tensor = mbase >> 9, head = (mbase >> 6) & 7, d0b = mbase & 63;
      unsigned short* dst = (tensor == 0) ? ktok + (size_t)l * NTOK * 64
                          : (tensor == 1) ? vtok + (size_t)l * NTOK * 64 : qtok;
      #pragma unroll
      for (int ni = 0; ni < 2; ni++) {
        const int n = pix0 + n_off + ni * 32 + l31;
        unsigned short* tokp = dst + (((size_t)b * 1024 + n) * 8 + head) * 64;
        #pragma unroll
        for (int q = 0; q < 4; q++) {
          const int rowoff = 8 * q + 4 * hi;
          const int m4 = mbase + rowoff;
          ushort4_t pk;
          #pragma unroll
          for (int e = 0; e < 4; e++) pk[e] = f2bf(acc[mi][ni][q * 4 + e] + bias[m4 + e]);
          *(ushort4_t*)&tokp[d0b + rowoff] = pk;
        }
      }
    }
  } else {
    // bf16 partials [s*256 + c][8192]
    #pragma unroll
    for (int mi = 0; mi < 2; mi++) {
      const int mbase = m0 + m_off + mi * 32;
      #pragma unroll
      for (int ni = 0; ni < 2; ni++) {
        const int n = n_off + ni * 32 + l31;
        #pragma unroll
        for (int q = 0; q < 4; q++) {
          const int rowoff = 8 * q + 4 * hi;
          unsigned short* orow = pout + (size_t)(s * 256 + mbase + rowoff) * 8192
                               + (size_t)b * 1024 + pix0 + n;
          #pragma unroll
          for (int e = 0; e < 4; e++) orow[(size_t)e * 8192] = f2bf(acc[mi][ni][q * 4 + e]);
        }
      }
    }
  }
}

// ---------------------------------------------------------------------------
// attention: 4 lanes/token, 16 tokens/wave (unchanged)
// ---------------------------------------------------------------------------
template<int L>
__global__ __launch_bounds__(256) void k_attn(const unsigned int* __restrict__ q_tok,
                                              const unsigned int* __restrict__ k_tok,
                                              const unsigned int* __restrict__ v_tok,
                                              unsigned int* __restrict__ opad) {
  constexpr int T = L + 2;
  const int lane = threadIdx.x & 63, wid = threadIdx.x >> 6;
  const int ti = lane >> 2, dq = lane & 3;
  const int token = blockIdx.x * 64 + wid * 16 + ti;
  const size_t rowq = (size_t)token * 32 + dq * 8;

  unsigned int q[8];
  *(uint4_t*)&q[0] = *(const uint4_t*)(q_tok + rowq);
  *(uint4_t*)&q[4] = *(const uint4_t*)(q_tok + rowq + 4);
  float qf[16];
  #pragma unroll
  for (int j = 0; j < 8; j++) {
    qf[2 * j]     = blo(q[j]);
    qf[2 * j + 1] = bhi(q[j]);
  }

  float s[T];
  s[T - 1] = 0.0f;
  #pragma unroll
  for (int t = 0; t <= L; t++) {
    const unsigned int* kp = k_tok + (size_t)t * (NTOK * 32) + rowq;
    unsigned int kk[8];
    *(uint4_t*)&kk[0] = *(const uint4_t*)kp;
    *(uint4_t*)&kk[4] = *(const uint4_t*)(kp + 4);
    float p = 0.0f;
    #pragma unroll
    for (int j = 0; j < 8; j++) {
      p = fmaf(qf[2 * j], blo(kk[j]), p);
      p = fmaf(qf[2 * j + 1], bhi(kk[j]), p);
    }
    p += __shfl_xor(p, 1);
    p += __shfl_xor(p, 2);
    s[t] = p;
  }

  float mx = s[0];
  #pragma unroll
  for (int t = 1; t < T; t++) mx = fmaxf(mx, s[t]);
  float attn[T], sum = 0.0f;
  #pragma unroll
  for (int t = 0; t < T; t++) { attn[t] = __expf(s[t] - mx); sum += attn[t]; }
  const float inv = 1.0f / sum;
  #pragma unroll
  for (int t = 0; t < T; t++) attn[t] *= inv;

  if constexpr (T == 5) {
    float m1 = attn[0], m2 = 1e30f;
    #pragma unroll
    for (int t = 1; t < 5; t++) {
      const float a = attn[t];
      const float nm1 = fminf(m1, a);
      m2 = fminf(m2, fmaxf(m1, a));
      m1 = nm1;
    }
    const float delta = m2 + 1e-7f;
    float ws = 0.0f;
    #pragma unroll
    for (int t = 0; t < 5; t++) { attn[t] = fmaxf(attn[t] - delta, 0.0f); ws += attn[t]; }
    const float r = 1.0f / (ws + 1e-7f);
    #pragma unroll
    for (int t = 0; t < 5; t++) attn[t] *= r;
  }

  float o[16];
  #pragma unroll
  for (int i = 0; i < 16; i++) o[i] = 0.0f;
  #pragma unroll
  for (int t = 0; t <= L; t++) {
    const unsigned int* vp = v_tok + (size_t)t * (NTOK * 32) + rowq;
    unsigned int vv[8];
    *(uint4_t*)&vv[0] = *(const uint4_t*)vp;
    *(uint4_t*)&vv[4] = *(const uint4_t*)(vp + 4);
    const float a = attn[t];
    #pragma unroll
    for (int j = 0; j < 8; j++) {
      o[2 * j]     = fmaf(a, blo(vv[j]), o[2 * j]);
      o[2 * j + 1] = fmaf(a, bhi(vv[j]), o[2 * j + 1]);
    }
  }

  unsigned int po[8];
  #pragma unroll
  for (int j = 0; j < 8; j++) {
    unsigned int r;
    asm("v_cvt_pk_bf16_f32 %0, %1, %2" : "=v"(r) : "v"(o[2 * j]), "v"(o[2 * j + 1]));
    po[j] = r;
  }
  const int head = token & 7, pix = token >> 3;
  const int b = pix >> 10, hw = pix & 1023, y = hw >> 5, x = hw & 31;
  unsigned int* dp = opad +
      (((size_t)b * 1156 + (y + 1) * 34 + (x + 1)) * 512 + head * 64 + dq * 16) / 2;
  *(uint4_t*)dp = *(uint4_t*)&po[0];
  *(uint4_t*)(dp + 4) = *(uint4_t*)&po[4];
}

// ---------------------------------------------------------------------------
// conv1 BN stats: v = sum of 4 bf16 partials + bias (same expr as bn_relu_pad)
// ---------------------------------------------------------------------------
__global__ __launch_bounds__(512) void k_comb_stats(const unsigned int* __restrict__ p,
    const float* __restrict__ bias1, const float* __restrict__ g, const float* __restrict__ bta,
    float* __restrict__ stats) {
  const int c = blockIdx.x, tid = threadIdx.x;
  const float bs = bias1[c];
  const unsigned int* P0 = p + (size_t)c * 4096;
  float s = 0.0f, ss = 0.0f;
  #pragma unroll
  for (int k2 = 0; k2 < 2; k2++) {
    const int j = (k2 * 512 + tid) * 4;
    uint4_t a0 = *(const uint4_t*)(P0 + j);
    uint4_t a1 = *(const uint4_t*)(P0 + 1048576 + j);
    uint4_t a2 = *(const uint4_t*)(P0 + 2097152 + j);
    uint4_t a3 = *(const uint4_t*)(P0 + 3145728 + j);
    #pragma unroll
    for (int e = 0; e < 4; e++) {
      const float vl = blo(a0[e]) + blo(a1[e]) + blo(a2[e]) + blo(a3[e]) + bs;
      const float vh = bhi(a0[e]) + bhi(a1[e]) + bhi(a2[e]) + bhi(a3[e]) + bs;
      s += vl + vh; ss += vl * vl + vh * vh;
    }
  }
  #pragma unroll
  for (int o2 = 32; o2 > 0; o2 >>= 1) { s += __shfl_xor(s, o2); ss += __shfl_xor(ss, o2); }
  __shared__ float rs[8], rss[8];
  const int wid = tid >> 6, lane = tid & 63;
  if (lane == 0) { rs[wid] = s; rss[wid] = ss; }
  __syncthreads();
  if (tid == 0) {
    float S = 0.0f, SS = 0.0f;
    #pragma unroll
    for (int w = 0; w < 8; w++) { S += rs[w]; SS += rss[w]; }
    const float m = S * (1.0f / 8192.0f);
    const float var = SS * (1.0f / 8192.0f) - m * m;
    const float A = g[c] * rsqrtf(var + 1e-5f);
    stats[c] = A;
    stats[256 + c] = bta[c] - m * A;
  }
}

// ---------------------------------------------------------------------------
// re-sum partials + bias + BN + ReLU + transpose -> padded channel-last h1pad
// ---------------------------------------------------------------------------
__global__ __launch_bounds__(512) void k_bn_relu_pad(const unsigned int* __restrict__ p,
    const float* __restrict__ bias1, const float* __restrict__ stats,
    unsigned short* __restrict__ hpad) {
  __shared__ unsigned short t[32][264];
  const int hw0 = blockIdx.x * 32, b = blockIdx.y, tid = threadIdx.x;
  const int u = tid & 15, cg = tid >> 4;
  const int base = ((b * 1024 + hw0) >> 1);
  #pragma unroll
  for (int i = 0; i < 8; i++) {
    const int ch = i * 32 + cg;
    const float bs = bias1[ch];
    const float A = stats[ch], Bt = stats[256 + ch];
    const size_t j = (size_t)ch * 4096 + base + u;
    const unsigned int a0 = p[j];
    const unsigned int a1 = p[j + 1048576];
    const unsigned int a2 = p[j + 2097152];
    const unsigned int a3 = p[j + 3145728];
    const float vl = blo(a0) + blo(a1) + blo(a2) + blo(a3) + bs;
    const float vh = bhi(a0) + bhi(a1) + bhi(a2) + bhi(a3) + bs;
    t[2 * u][ch]     = f2bf(fmaxf(vl * A + Bt, 0.0f));
    t[2 * u + 1][ch] = f2bf(fmaxf(vh * A + Bt, 0.0f));
  }
  __syncthreads();
  const int px = tid >> 4, c0 = (tid & 15) * 16;
  const int y = hw0 >> 5, x = hw0 & 31;
  unsigned short* dp = hpad + ((size_t)b * 1156 + (y + 1) * 34 + (x + px + 1)) * 256 + c0;
  short8 v0, v1;
  #pragma unroll
  for (int i = 0; i < 8; i++) { v0[i] = (short)t[px][c0 + i]; v1[i] = (short)t[px][c0 + 8 + i]; }
  *(short8*)dp = v0; *(short8*)(dp + 8) = v1;
}

// ---------------------------------------------------------------------------
// conv2 combine: xacc += gamma * (sum of 4 bf16 partials + bias); refresh xcl
// ---------------------------------------------------------------------------
__global__ __launch_bounds__(512) void k_comb2(const unsigned int* __restrict__ p,
    const float* __restrict__ bias2, const float* __restrict__ gamma_p, int last,
    float* __restrict__ xacc, unsigned short* __restrict__ xcl) {
  __shared__ unsigned short t[32][264];
  const int hw0 = blockIdx.x * 32, b = blockIdx.y, tid = threadIdx.x;
  const int u = tid & 15, cg = tid >> 4;
  const float gmm = gamma_p[0];
  const int base = ((b * 1024 + hw0) >> 1);
  #pragma unroll
  for (int i = 0; i < 8; i++) {
    const int ch = i * 32 + cg;
    const float bs = bias2[ch];
    const size_t j = (size_t)ch * 4096 + base + u;
    const unsigned int a0 = p[j];
    const unsigned int a1 = p[j + 1048576];
    const unsigned int a2 = p[j + 2097152];
    const unsigned int a3 = p[j + 3145728];
    const float vl = blo(a0) + blo(a1) + blo(a2) + blo(a3) + bs;
    const float vh = bhi(a0) + bhi(a1) + bhi(a2) + bhi(a3) + bs;
    float* X = xacc + ((size_t)b * 256 + ch) * 1024 + hw0 + 2 * u;
    f32x2 xv = *(const f32x2*)X;
    const float xl = xv[0] + gmm * vl;
    const float xh = xv[1] + gmm * vh;
    f32x2 xw = {xl, xh};
    *(f32x2*)X = xw;
    t[2 * u][ch]     = f2bf(xl);
    t[2 * u + 1][ch] = f2bf(xh);
  }
  __syncthreads();
  if (!last) {
    const int px = tid >> 4, c0 = (tid & 15) * 16;
    unsigned short* dp = xcl + ((size_t)b * 1024 + hw0 + px) * 256 + c0;
    short8 v0, v1;
    #pragma unroll
    for (int i = 0; i < 8; i++) { v0[i] = (short)t[px][c0 + i]; v1[i] = (short)t[px][c0 + 8 + i]; }
    *(short8*)dp = v0; *(short8*)(dp + 8) = v1;
  }
}

// ---------------------------------------------------------------------------
extern "C" void kernel_launch(void* const* d_in, const int* in_sizes, int n_in,
                              void* d_out, int out_size, void* d_ws, size_t ws_size,
                              hipStream_t stream) {
  (void)in_sizes; (void)n_in; (void)out_size;
  const float* x_in   = (const float*)d_in[0];
  const float* kw     = (const float*)d_in[1];
  const float* kb     = (const float*)d_in[2];
  const float* qw     = (const float*)d_in[3];
  const float* qb     = (const float*)d_in[4];
  const float* vw     = (const float*)d_in[5];
  const float* vb     = (const float*)d_in[6];
  const float* ow1    = (const float*)d_in[7];
  const float* ob1    = (const float*)d_in[8];
  const float* bn_g   = (const float*)d_in[9];
  const float* bn_b   = (const float*)d_in[10];
  const float* ow2    = (const float*)d_in[11];
  const float* ob2    = (const float*)d_in[12];
  const float* gammas = (const float*)d_in[13];

  char* ws = (char*)d_ws;
  size_t off = 0;
  auto alloc = [&](size_t bytes) -> void* {
    void* pp = ws + off;
    off += (bytes + 255) & ~(size_t)255;
    return pp;
  };
  unsigned short* xcl     = (unsigned short*)alloc((size_t)NPIX * 256 * 2);
  unsigned short* k_tok   = (unsigned short*)alloc((size_t)4 * NTOK * 64 * 2);
  unsigned short* v_tok   = (unsigned short*)alloc((size_t)4 * NTOK * 64 * 2);
  unsigned short* q_tok   = (unsigned short*)alloc((size_t)NTOK * 64 * 2);
  unsigned short* opad    = (unsigned short*)alloc((size_t)8 * 1156 * 512 * 2);
  unsigned short* h1pad   = (unsigned short*)alloc((size_t)8 * 1156 * 256 * 2);
  unsigned short* p1      = (unsigned short*)alloc((size_t)4 * 256 * 8192 * 2);
  float*          stats   = (float*)alloc(512 * 4);
  unsigned short* wkqv    = (unsigned short*)alloc((size_t)4 * 3 * 512 * 256 * 2);
  unsigned short* w1bf    = (unsigned short*)alloc((size_t)1024 * 4608 * 2);
  unsigned short* w2bf    = (unsigned short*)alloc((size_t)1024 * 2304 * 2);
  float*          biascat = (float*)alloc((size_t)6144 * 4);
  if (off > ws_size) return;

  float* xacc = (float*)d_out;

  k_prep<<<PREP_TOT, 256, 0, stream>>>(
      kw, vw, qw, ow1, ow2, kb, vb, qb,
      wkqv, w1bf, w2bf, biascat,
      (unsigned int*)opad, (unsigned int*)h1pad,
      x_in, xacc, xcl);

  for (int l = 0; l < 4; l++) {
    k_gemm<0, 4, 256, 256, 1><<<768, 256, 0, stream>>>(
        wkqv + (size_t)l * 3 * 512 * 256, xcl, biascat + l * 1536, l,
        k_tok, v_tok, q_tok, nullptr);
    const unsigned int* qt = (const unsigned int*)q_tok;
    const unsigned int* kt = (const unsigned int*)k_tok;
    const unsigned int* vt = (const unsigned int*)v_tok;
    unsigned int* op = (unsigned int*)opad;
    switch (l) {
      case 0: k_attn<0><<<1024, 256, 0, stream>>>(qt, kt, vt, op); break;
      case 1: k_attn<1><<<1024, 256, 0, stream>>>(qt, kt, vt, op); break;
      case 2: k_attn<2><<<1024, 256, 0, stream>>>(qt, kt, vt, op); break;
      default: k_attn<3><<<1024, 256, 0, stream>>>(qt, kt, vt, op); break;
    }
    k_gemm<1, 18, 4608, 512, 2><<<512, 256, 0, stream>>>(
        w1bf + (size_t)l * 256 * 4608, opad, nullptr, l,
        nullptr, nullptr, nullptr, p1);
    k_comb_stats<<<256, 512, 0, stream>>>((const unsigned int*)p1, ob1 + l * 256,
                                          bn_g + l * 256, bn_b + l * 256, stats);
    k_bn_relu_pad<<<dim3(32, 8), 512, 0, stream>>>((const unsigned int*)p1,
                                                   ob1 + l * 256, stats, h1pad);
    k_gemm<2, 9, 2304, 256, 2><<<512, 256, 0, stream>>>(
        w2bf + (size_t)l * 256 * 2304, h1pad, nullptr, l,
        nullptr, nullptr, nullptr, p1);
    k_comb2<<<dim3(32, 8), 512, 0, stream>>>((const unsigned int*)p1, ob2 + l * 256,
                                             gammas + l, (l == 3) ? 1 : 0, xacc, xcl);
  }
}

// Round 13
// 349.046 us; speedup vs baseline: 1.4345x; 1.0657x over previous
//
#include <hip/hip_runtime.h>

// ---------------------------------------------------------------------------
// AttentiveDensenet on MI355X (gfx950) — round 13: REVERT to round-10 config
// (best measured: 349.8 µs). 16x16x32 MFMA, 128x128 tiles, K-step 64,
// row-major XOR-swizzled LDS + global_load_lds staging; QKV single-buffered;
// split-K 4 bf16 partials; fused combines; one-dispatch prep.
// B=8, C=256, H=W=32 (HW=1024), L=4, NH=8, K=V=64.
// ---------------------------------------------------------------------------

typedef __attribute__((ext_vector_type(8))) short short8;
typedef __attribute__((ext_vector_type(4))) float f32x4;
typedef __attribute__((ext_vector_type(2))) float f32x2;
typedef __attribute__((ext_vector_type(4))) unsigned short ushort4_t;
typedef __attribute__((ext_vector_type(4))) unsigned int uint4_t;

#define NTOK 65536   // B*HW*NH
#define NPIX 8192    // B*HW

// prep block layout: [0,7752) flat (kqv cast + bias + borders);
// [7752,8776) w1 rows; [8776,9800) w2 rows; [9800,9928) x->xacc/xcl
#define PREP_FLAT 7752
#define PREP_W1   (PREP_FLAT + 1024)
#define PREP_W2   (PREP_W1 + 1024)
#define PREP_TOT  (PREP_W2 + 128)

__device__ __forceinline__ float bf2f(unsigned short u) {
  unsigned int v = ((unsigned int)u) << 16;
  float f; __builtin_memcpy(&f, &v, 4); return f;
}
__device__ __forceinline__ unsigned short f2bf(float f) {
  unsigned int u; __builtin_memcpy(&u, &f, 4);
  u = (u + 0x7FFFu + ((u >> 16) & 1u)) >> 16;
  return (unsigned short)u;
}
__device__ __forceinline__ float blo(unsigned int u) {
  unsigned int v = u << 16; float f; __builtin_memcpy(&f, &v, 4); return f;
}
__device__ __forceinline__ float bhi(unsigned int u) {
  unsigned int v = u & 0xFFFF0000u; float f; __builtin_memcpy(&f, &v, 4); return f;
}

__device__ __forceinline__ void gl_lds16(const unsigned short* g, const unsigned short* l) {
  __builtin_amdgcn_global_load_lds(
      (const __attribute__((address_space(1))) unsigned int*)g,
      (__attribute__((address_space(3))) unsigned int*)l, 16, 0, 0);
}

// ---------------------------------------------------------------------------
// one-shot prep. q-scale (1/sqrt(64)=0.125, exact) folded into qw/qb.
// Weight reorder [m][c][tap] -> [m][tap][c] via LDS (both sides coalesced).
// ---------------------------------------------------------------------------
__global__ void k_prep(const float* __restrict__ kw, const float* __restrict__ vw,
                       const float* __restrict__ qw, const float* __restrict__ ow1,
                       const float* __restrict__ ow2, const float* __restrict__ kb,
                       const float* __restrict__ vb, const float* __restrict__ qb,
                       unsigned short* __restrict__ wkqv, unsigned short* __restrict__ w1,
                       unsigned short* __restrict__ w2, float* __restrict__ biascat,
                       unsigned int* __restrict__ opad_u32, unsigned int* __restrict__ h1pad_u32,
                       const float* __restrict__ x_in, float* __restrict__ xacc,
                       unsigned short* __restrict__ xcl) {
  const int bid = blockIdx.x;
  const int tid = threadIdx.x;

  if (bid < PREP_FLAT) {
    long i = (long)bid * 256 + tid;
    if (i < 1572864) {
      int idx = (int)(i & 131071); int sl = (int)(i >> 17); int slot = sl % 3, l = sl / 3;
      const float* s = slot == 0 ? kw : slot == 1 ? vw : qw;
      float v = s[(size_t)l * 131072 + idx];
      if (slot == 2) v *= 0.125f;
      wkqv[i] = f2bf(v);
      return;
    }
    i -= 1572864;
    if (i < 6144) {
      int o = (int)(i & 511); int sl = (int)(i >> 9); int slot = sl % 3, l = sl / 3;
      const float* s = slot == 0 ? kb : slot == 1 ? vb : qb;
      float v = s[l * 512 + o];
      if (slot == 2) v *= 0.125f;
      biascat[i] = v;
      return;
    }
    i -= 6144;
    auto border_pix = [](int pidx) -> size_t {
      const int b = pidx / 132, t = pidx % 132;
      int y, x;
      if (t < 34) { y = 0; x = t; }
      else if (t < 68) { y = 33; x = t - 34; }
      else { const int j = t - 68; y = 1 + (j >> 1); x = (j & 1) * 33; }
      return (size_t)b * 1156 + y * 34 + x;
    };
    if (i < 270336) {                   // opad borders: 1056 px x 256 u32
      const int pidx = (int)(i >> 8), c = (int)(i & 255);
      opad_u32[border_pix(pidx) * 256 + c] = 0u;
      return;
    }
    i -= 270336;
    if (i < 135168) {                   // h1pad borders: 1056 px x 128 u32
      const int pidx = (int)(i >> 7), c = (int)(i & 127);
      h1pad_u32[border_pix(pidx) * 128 + c] = 0u;
    }
    return;
  }

  if (bid < PREP_W1) {
    // w1 row m: read 4608 f32 linear -> LDS bf16; write permuted [tap*512+c]
    __shared__ unsigned short lds[4608];
    const int m = bid - PREP_FLAT;
    const float* src = ow1 + (size_t)m * 4608;
    #pragma unroll
    for (int k = 0; k < 18; k++) lds[k * 256 + tid] = f2bf(src[k * 256 + tid]);
    __syncthreads();
    unsigned int* dst = (unsigned int*)(w1 + (size_t)m * 4608);
    #pragma unroll
    for (int j = 0; j < 9; j++) {
      const int u = j * 256 + tid;
      const int o = 2 * u;                 // o even -> c even -> c+1 in range
      const int tap = o >> 9, c = o & 511;
      dst[u] = (unsigned int)lds[c * 9 + tap] |
               ((unsigned int)lds[(c + 1) * 9 + tap] << 16);
    }
    return;
  }

  if (bid < PREP_W2) {
    __shared__ unsigned short lds2[2304];
    const int m = bid - PREP_W1;
    const float* src = ow2 + (size_t)m * 2304;
    #pragma unroll
    for (int k = 0; k < 9; k++) lds2[k * 256 + tid] = f2bf(src[k * 256 + tid]);
    __syncthreads();
    unsigned int* dst = (unsigned int*)(w2 + (size_t)m * 2304);
    #pragma unroll
    for (int j = 0; j < 5; j++) {
      const int u = j * 256 + tid;
      if (u < 1152) {
        const int o = 2 * u;
        const int tap = o >> 8, c = o & 255;
        dst[u] = (unsigned int)lds2[c * 9 + tap] |
                 ((unsigned int)lds2[(c + 1) * 9 + tap] << 16);
      }
    }
    return;
  }

  // ---- x (f32 [B][256][1024]) -> xacc copy + xcl (bf16 [B][1024][256]) ----
  {
    __shared__ unsigned short t[64][68];
    const int xb = bid - PREP_W2;          // 128 blocks
    const int hw0 = (xb & 15) * 64, b = xb >> 4;
    for (int cc = 0; cc < 4; cc++) {
      __syncthreads();
      {
        const int px = tid & 63, c = tid >> 6;
        #pragma unroll
        for (int i = 0; i < 16; i++) {
          const size_t idx = ((size_t)b * 256 + cc * 64 + c + i * 4) * 1024 + hw0 + px;
          const float v = x_in[idx];
          xacc[idx] = v;
          t[px][c + i * 4] = f2bf(v);
        }
      }
      __syncthreads();
      {
        const int px = tid >> 2, c0 = (tid & 3) * 16;
        unsigned short* dp = xcl + ((size_t)b * 1024 + hw0 + px) * 256 + cc * 64 + c0;
        short8 v0, v1;
        #pragma unroll
        for (int i = 0; i < 8; i++) { v0[i] = (short)t[px][c0 + i]; v1[i] = (short)t[px][c0 + 8 + i]; }
        *(short8*)dp = v0; *(short8*)(dp + 8) = v1;
      }
    }
  }
}

// ---------------------------------------------------------------------------
// MFMA GEMM: 128x128 tile, 4 waves, K-step 64, global_load_lds staging.
// NBUF=2: double-buffered (64KB) — convs. NBUF=1: single (32KB) — QKV.
// MODE 0: QKV dense K=256 -> token-major k/v/q (+bias).
// MODE 1: conv1 CIN=512, split-K 4 (SW=128) -> bf16 partials.
// MODE 2: conv2 CIN=256, split-K 4 (SW=64)  -> bf16 partials.
// ---------------------------------------------------------------------------
template<int MODE, int NSTEP, int KDIM, int CIN, int NBUF>
__global__ __launch_bounds__(256) void k_gemm(
    const unsigned short* __restrict__ W,
    const unsigned short* __restrict__ act,
    const float* __restrict__ bias,
    int l,
    unsigned short* __restrict__ ktok, unsigned short* __restrict__ vtok,
    unsigned short* __restrict__ qtok,
    unsigned short* __restrict__ pout) {
  __shared__ unsigned short sm[NBUF][2][8192];   // [buf][A/B][128 rows x 64 k]

  const int bid = blockIdx.x;
  int m0, b, pix0, s;
  if constexpr (MODE == 0) {
    const int xcd = bid & 7, li = bid >> 3;
    const int nt = xcd * 8 + (li & 7);
    m0 = (li >> 3) * 128; s = 0;
    b = nt >> 3; pix0 = (nt & 7) * 128;
  } else {
    const int xcd = bid & 7, li = bid >> 3;
    const int nt = xcd * 8 + (li & 7);
    const int r = li >> 3;
    m0 = (r & 1) * 128; s = r >> 1;
    b = nt >> 3; pix0 = (nt & 7) * 128;
  }
  constexpr int SW = (MODE == 1) ? 128 : 64;

  const int tid = threadIdx.x;
  const int wid = tid >> 6, lane = tid & 63;
  const int lr = lane & 15, lg = lane >> 4;
  const int m_off = (wid >> 1) * 64, n_off = (wid & 1) * 64;

  const unsigned short* gA[4];
  const unsigned short* gB[4];
  #pragma unroll
  for (int j = 0; j < 4; j++) {
    const int o = (wid * 4 + j) * 512 + lane * 8;
    const int row = o >> 6;
    const int ksw = (((o >> 3) & 7) ^ (row & 7)) * 8;
    gA[j] = W + (size_t)(m0 + row) * KDIM + (MODE ? s * SW : 0) + ksw;
    if constexpr (MODE == 0) {
      gB[j] = act + ((size_t)b * 1024 + pix0 + row) * 256 + ksw;
    } else {
      const int pix = pix0 + row, py = pix >> 5, px = pix & 31;
      gB[j] = act + (size_t)b * 1156 * CIN + ((size_t)py * 34 + px) * CIN + s * SW + ksw;
    }
  }

  auto offA = [&](int st) -> int {
    if constexpr (MODE == 0) return st * 64;
    else if constexpr (MODE == 1) return (st >> 1) * 512 + (st & 1) * 64;
    else return st * 256;
  };
  auto offB = [&](int st) -> int {
    if constexpr (MODE == 0) return st * 64;
    else if constexpr (MODE == 1) {
      const int tap = st >> 1, dy = tap / 3, dx = tap - dy * 3;
      return (dy * 34 + dx) * 512 + (st & 1) * 64;
    } else {
      const int dy = st / 3, dx = st - dy * 3;
      return (dy * 34 + dx) * 256;
    }
  };
  auto STAGE = [&](int bf, int st) {
    const int oa = offA(st), ob = offB(st);
    #pragma unroll
    for (int j = 0; j < 4; j++) gl_lds16(gA[j] + oa, &sm[bf][0][(wid * 4 + j) * 512]);
    #pragma unroll
    for (int j = 0; j < 4; j++) gl_lds16(gB[j] + ob, &sm[bf][1][(wid * 4 + j) * 512]);
  };
  auto COMPUTE = [&](int cur, f32x4 (*acc)[4]) {
    #pragma unroll
    for (int ks = 0; ks < 2; ks++) {
      short8 af[4], bfr[4];
      #pragma unroll
      for (int i = 0; i < 4; i++) {
        const int ra = m_off + i * 16 + lr;
        af[i] = *(const short8*)&sm[cur][0][ra * 64 + (((ks * 4 + lg) ^ (ra & 7)) * 8)];
        const int rb = n_off + i * 16 + lr;
        bfr[i] = *(const short8*)&sm[cur][1][rb * 64 + (((ks * 4 + lg) ^ (rb & 7)) * 8)];
      }
      #pragma unroll
      for (int i = 0; i < 4; i++)
        #pragma unroll
        for (int jn = 0; jn < 4; jn++)
          acc[i][jn] = __builtin_amdgcn_mfma_f32_16x16x32_bf16(af[i], bfr[jn], acc[i][jn], 0, 0, 0);
    }
  };

  f32x4 acc[4][4] = {};

  if constexpr (NBUF == 2) {
    STAGE(0, 0);
    __syncthreads();
    #pragma unroll
    for (int st = 0; st < NSTEP; st++) {
      if (st + 1 < NSTEP) STAGE((st + 1) & 1, st + 1);
      COMPUTE(st & 1, acc);
      __syncthreads();
    }
  } else {
    #pragma unroll
    for (int st = 0; st < NSTEP; st++) {
      if (st) __syncthreads();
      STAGE(0, st);
      __syncthreads();
      COMPUTE(0, acc);
    }
  }

  if constexpr (MODE == 0) {
    #pragma unroll
    for (int mi = 0; mi < 4; mi++) {
      const int mb = m0 + m_off + mi * 16 + lg * 4;
      const int tensor = mb >> 9, head = (mb >> 6) & 7, d0 = mb & 63;
      unsigned short* dst = (tensor == 0) ? ktok + (size_t)l * NTOK * 64
                          : (tensor == 1) ? vtok + (size_t)l * NTOK * 64 : qtok;
      const float b0 = bias[mb], b1 = bias[mb + 1], b2 = bias[mb + 2], b3 = bias[mb + 3];
      #pragma unroll
      for (int ni = 0; ni < 4; ni++) {
        const int n = pix0 + n_off + ni * 16 + lr;
        ushort4_t pk;
        pk[0] = f2bf(acc[mi][ni][0] + b0); pk[1] = f2bf(acc[mi][ni][1] + b1);
        pk[2] = f2bf(acc[mi][ni][2] + b2); pk[3] = f2bf(acc[mi][ni][3] + b3);
        *(ushort4_t*)&dst[(((size_t)b * 1024 + n) * 8 + head) * 64 + d0] = pk;
      }
    }
  } else {
    // bf16 partials [s*256 + c][8192]
    #pragma unroll
    for (int mi = 0; mi < 4; mi++) {
      const int mb = m0 + m_off + mi * 16 + lg * 4;
      unsigned short* orow = pout + (size_t)(s * 256 + mb) * 8192 + (size_t)b * 1024 + pix0;
      #pragma unroll
      for (int ni = 0; ni < 4; ni++) {
        const int n = n_off + ni * 16 + lr;
        #pragma unroll
        for (int r = 0; r < 4; r++) orow[(size_t)r * 8192 + n] = f2bf(acc[mi][ni][r]);
      }
    }
  }
}

// ---------------------------------------------------------------------------
// attention: 4 lanes/token, 16 tokens/wave. q pre-scaled by 1/sqrt(K) in prep.
// ---------------------------------------------------------------------------
template<int L>
__global__ __launch_bounds__(256) void k_attn(const unsigned int* __restrict__ q_tok,
                                              const unsigned int* __restrict__ k_tok,
                                              const unsigned int* __restrict__ v_tok,
                                              unsigned int* __restrict__ opad) {
  constexpr int T = L + 2;
  const int lane = threadIdx.x & 63, wid = threadIdx.x >> 6;
  const int ti = lane >> 2, dq = lane & 3;
  const int token = blockIdx.x * 64 + wid * 16 + ti;
  const size_t rowq = (size_t)token * 32 + dq * 8;

  unsigned int q[8];
  *(uint4_t*)&q[0] = *(const uint4_t*)(q_tok + rowq);
  *(uint4_t*)&q[4] = *(const uint4_t*)(q_tok + rowq + 4);
  float qf[16];
  #pragma unroll
  for (int j = 0; j < 8; j++) {
    qf[2 * j]     = blo(q[j]);
    qf[2 * j + 1] = bhi(q[j]);
  }

  float s[T];
  s[T - 1] = 0.0f;
  #pragma unroll
  for (int t = 0; t <= L; t++) {
    const unsigned int* kp = k_tok + (size_t)t * (NTOK * 32) + rowq;
    unsigned int kk[8];
    *(uint4_t*)&kk[0] = *(const uint4_t*)kp;
    *(uint4_t*)&kk[4] = *(const uint4_t*)(kp + 4);
    float p = 0.0f;
    #pragma unroll
    for (int j = 0; j < 8; j++) {
      p = fmaf(qf[2 * j], blo(kk[j]), p);
      p = fmaf(qf[2 * j + 1], bhi(kk[j]), p);
    }
    p += __shfl_xor(p, 1);
    p += __shfl_xor(p, 2);
    s[t] = p;
  }

  float mx = s[0];
  #pragma unroll
  for (int t = 1; t < T; t++) mx = fmaxf(mx, s[t]);
  float attn[T], sum = 0.0f;
  #pragma unroll
  for (int t = 0; t < T; t++) { attn[t] = __expf(s[t] - mx); sum += attn[t]; }
  const float inv = 1.0f / sum;
  #pragma unroll
  for (int t = 0; t < T; t++) attn[t] *= inv;

  if constexpr (T == 5) {
    float m1 = attn[0], m2 = 1e30f;
    #pragma unroll
    for (int t = 1; t < 5; t++) {
      const float a = attn[t];
      const float nm1 = fminf(m1, a);
      m2 = fminf(m2, fmaxf(m1, a));
      m1 = nm1;
    }
    const float delta = m2 + 1e-7f;
    float ws = 0.0f;
    #pragma unroll
    for (int t = 0; t < 5; t++) { attn[t] = fmaxf(attn[t] - delta, 0.0f); ws += attn[t]; }
    const float r = 1.0f / (ws + 1e-7f);
    #pragma unroll
    for (int t = 0; t < 5; t++) attn[t] *= r;
  }

  float o[16];
  #pragma unroll
  for (int i = 0; i < 16; i++) o[i] = 0.0f;
  #pragma unroll
  for (int t = 0; t <= L; t++) {
    const unsigned int* vp = v_tok + (size_t)t * (NTOK * 32) + rowq;
    unsigned int vv[8];
    *(uint4_t*)&vv[0] = *(const uint4_t*)vp;
    *(uint4_t*)&vv[4] = *(const uint4_t*)(vp + 4);
    const float a = attn[t];
    #pragma unroll
    for (int j = 0; j < 8; j++) {
      o[2 * j]     = fmaf(a, blo(vv[j]), o[2 * j]);
      o[2 * j + 1] = fmaf(a, bhi(vv[j]), o[2 * j + 1]);
    }
  }

  unsigned int po[8];
  #pragma unroll
  for (int j = 0; j < 8; j++) {
    unsigned int r;
    asm("v_cvt_pk_bf16_f32 %0, %1, %2" : "=v"(r) : "v"(o[2 * j]), "v"(o[2 * j + 1]));
    po[j] = r;
  }
  const int head = token & 7, pix = token >> 3;
  const int b = pix >> 10, hw = pix & 1023, y = hw >> 5, x = hw & 31;
  unsigned int* dp = opad +
      (((size_t)b * 1156 + (y + 1) * 34 + (x + 1)) * 512 + head * 64 + dq * 16) / 2;
  *(uint4_t*)dp = *(uint4_t*)&po[0];
  *(uint4_t*)(dp + 4) = *(uint4_t*)&po[4];
}

// ---------------------------------------------------------------------------
// conv1 BN stats: v = sum of 4 bf16 partials + bias (same expr as bn_relu_pad)
// ---------------------------------------------------------------------------
__global__ __launch_bounds__(512) void k_comb_stats(const unsigned int* __restrict__ p,
    const float* __restrict__ bias1, const float* __restrict__ g, const float* __restrict__ bta,
    float* __restrict__ stats) {
  const int c = blockIdx.x, tid = threadIdx.x;
  const float bs = bias1[c];
  const unsigned int* P0 = p + (size_t)c * 4096;
  float s = 0.0f, ss = 0.0f;
  #pragma unroll
  for (int k2 = 0; k2 < 2; k2++) {
    const int j = (k2 * 512 + tid) * 4;
    uint4_t a0 = *(const uint4_t*)(P0 + j);
    uint4_t a1 = *(const uint4_t*)(P0 + 1048576 + j);
    uint4_t a2 = *(const uint4_t*)(P0 + 2097152 + j);
    uint4_t a3 = *(const uint4_t*)(P0 + 3145728 + j);
    #pragma unroll
    for (int e = 0; e < 4; e++) {
      const float vl = blo(a0[e]) + blo(a1[e]) + blo(a2[e]) + blo(a3[e]) + bs;
      const float vh = bhi(a0[e]) + bhi(a1[e]) + bhi(a2[e]) + bhi(a3[e]) + bs;
      s += vl + vh; ss += vl * vl + vh * vh;
    }
  }
  #pragma unroll
  for (int o2 = 32; o2 > 0; o2 >>= 1) { s += __shfl_xor(s, o2); ss += __shfl_xor(ss, o2); }
  __shared__ float rs[8], rss[8];
  const int wid = tid >> 6, lane = tid & 63;
  if (lane == 0) { rs[wid] = s; rss[wid] = ss; }
  __syncthreads();
  if (tid == 0) {
    float S = 0.0f, SS = 0.0f;
    #pragma unroll
    for (int w = 0; w < 8; w++) { S += rs[w]; SS += rss[w]; }
    const float m = S * (1.0f / 8192.0f);
    const float var = SS * (1.0f / 8192.0f) - m * m;
    const float A = g[c] * rsqrtf(var + 1e-5f);
    stats[c] = A;
    stats[256 + c] = bta[c] - m * A;
  }
}

// ---------------------------------------------------------------------------
// re-sum partials + bias + BN + ReLU + transpose -> padded channel-last h1pad
// ---------------------------------------------------------------------------
__global__ __launch_bounds__(512) void k_bn_relu_pad(const unsigned int* __restrict__ p,
    const float* __restrict__ bias1, const float* __restrict__ stats,
    unsigned short* __restrict__ hpad) {
  __shared__ unsigned short t[32][264];
  const int hw0 = blockIdx.x * 32, b = blockIdx.y, tid = threadIdx.x;
  const int u = tid & 15, cg = tid >> 4;
  const int base = ((b * 1024 + hw0) >> 1);
  #pragma unroll
  for (int i = 0; i < 8; i++) {
    const int ch = i * 32 + cg;
    const float bs = bias1[ch];
    const float A = stats[ch], Bt = stats[256 + ch];
    const size_t j = (size_t)ch * 4096 + base + u;
    const unsigned int a0 = p[j];
    const unsigned int a1 = p[j + 1048576];
    const unsigned int a2 = p[j + 2097152];
    const unsigned int a3 = p[j + 3145728];
    const float vl = blo(a0) + blo(a1) + blo(a2) + blo(a3) + bs;
    const float vh = bhi(a0) + bhi(a1) + bhi(a2) + bhi(a3) + bs;
    t[2 * u][ch]     = f2bf(fmaxf(vl * A + Bt, 0.0f));
    t[2 * u + 1][ch] = f2bf(fmaxf(vh * A + Bt, 0.0f));
  }
  __syncthreads();
  const int px = tid >> 4, c0 = (tid & 15) * 16;
  const int y = hw0 >> 5, x = hw0 & 31;
  unsigned short* dp = hpad + ((size_t)b * 1156 + (y + 1) * 34 + (x + px + 1)) * 256 + c0;
  short8 v0, v1;
  #pragma unroll
  for (int i = 0; i < 8; i++) { v0[i] = (short)t[px][c0 + i]; v1[i] = (short)t[px][c0 + 8 + i]; }
  *(short8*)dp = v0; *(short8*)(dp + 8) = v1;
}

// ---------------------------------------------------------------------------
// conv2 combine: xacc += gamma * (sum of 4 bf16 partials + bias); refresh xcl
// ---------------------------------------------------------------------------
__global__ __launch_bounds__(512) void k_comb2(const unsigned int* __restrict__ p,
    const float* __restrict__ bias2, const float* __restrict__ gamma_p, int last,
    float* __restrict__ xacc, unsigned short* __restrict__ xcl) {
  __shared__ unsigned short t[32][264];
  const int hw0 = blockIdx.x * 32, b = blockIdx.y, tid = threadIdx.x;
  const int u = tid & 15, cg = tid >> 4;
  const float gmm = gamma_p[0];
  const int base = ((b * 1024 + hw0) >> 1);
  #pragma unroll
  for (int i = 0; i < 8; i++) {
    const int ch = i * 32 + cg;
    const float bs = bias2[ch];
    const size_t j = (size_t)ch * 4096 + base + u;
    const unsigned int a0 = p[j];
    const unsigned int a1 = p[j + 1048576];
    const unsigned int a2 = p[j + 2097152];
    const unsigned int a3 = p[j + 3145728];
    const float vl = blo(a0) + blo(a1) + blo(a2) + blo(a3) + bs;
    const float vh = bhi(a0) + bhi(a1) + bhi(a2) + bhi(a3) + bs;
    float* X = xacc + ((size_t)b * 256 + ch) * 1024 + hw0 + 2 * u;
    f32x2 xv = *(const f32x2*)X;
    const float xl = xv[0] + gmm * vl;
    const float xh = xv[1] + gmm * vh;
    f32x2 xw = {xl, xh};
    *(f32x2*)X = xw;
    t[2 * u][ch]     = f2bf(xl);
    t[2 * u + 1][ch] = f2bf(xh);
  }
  __syncthreads();
  if (!last) {
    const int px = tid >> 4, c0 = (tid & 15) * 16;
    unsigned short* dp = xcl + ((size_t)b * 1024 + hw0 + px) * 256 + c0;
    short8 v0, v1;
    #pragma unroll
    for (int i = 0; i < 8; i++) { v0[i] = (short)t[px][c0 + i]; v1[i] = (short)t[px][c0 + 8 + i]; }
    *(short8*)dp = v0; *(short8*)(dp + 8) = v1;
  }
}

// ---------------------------------------------------------------------------
extern "C" void kernel_launch(void* const* d_in, const int* in_sizes, int n_in,
                              void* d_out, int out_size, void* d_ws, size_t ws_size,
                              hipStream_t stream) {
  (void)in_sizes; (void)n_in; (void)out_size;
  const float* x_in   = (const float*)d_in[0];
  const float* kw     = (const float*)d_in[1];
  const float* kb     = (const float*)d_in[2];
  const float* qw     = (const float*)d_in[3];
  const float* qb     = (const float*)d_in[4];
  const float* vw     = (const float*)d_in[5];
  const float* vb     = (const float*)d_in[6];
  const float* ow1    = (const float*)d_in[7];
  const float* ob1    = (const float*)d_in[8];
  const float* bn_g   = (const float*)d_in[9];
  const float* bn_b   = (const float*)d_in[10];
  const float* ow2    = (const float*)d_in[11];
  const float* ob2    = (const float*)d_in[12];
  const float* gammas = (const float*)d_in[13];

  char* ws = (char*)d_ws;
  size_t off = 0;
  auto alloc = [&](size_t bytes) -> void* {
    void* pp = ws + off;
    off += (bytes + 255) & ~(size_t)255;
    return pp;
  };
  unsigned short* xcl     = (unsigned short*)alloc((size_t)NPIX * 256 * 2);
  unsigned short* k_tok   = (unsigned short*)alloc((size_t)4 * NTOK * 64 * 2);
  unsigned short* v_tok   = (unsigned short*)alloc((size_t)4 * NTOK * 64 * 2);
  unsigned short* q_tok   = (unsigned short*)alloc((size_t)NTOK * 64 * 2);
  unsigned short* opad    = (unsigned short*)alloc((size_t)8 * 1156 * 512 * 2);
  unsigned short* h1pad   = (unsigned short*)alloc((size_t)8 * 1156 * 256 * 2);
  unsigned short* p1      = (unsigned short*)alloc((size_t)4 * 256 * 8192 * 2);
  float*          stats   = (float*)alloc(512 * 4);
  unsigned short* wkqv    = (unsigned short*)alloc((size_t)4 * 3 * 512 * 256 * 2);
  unsigned short* w1bf    = (unsigned short*)alloc((size_t)1024 * 4608 * 2);
  unsigned short* w2bf    = (unsigned short*)alloc((size_t)1024 * 2304 * 2);
  float*          biascat = (float*)alloc((size_t)6144 * 4);
  if (off > ws_size) return;

  float* xacc = (float*)d_out;

  // one dispatch: weights (LDS-permuted reorder) + biases + borders + x conv
  k_prep<<<PREP_TOT, 256, 0, stream>>>(
      kw, vw, qw, ow1, ow2, kb, vb, qb,
      wkqv, w1bf, w2bf, biascat,
      (unsigned int*)opad, (unsigned int*)h1pad,
      x_in, xacc, xcl);

  for (int l = 0; l < 4; l++) {
    k_gemm<0, 4, 256, 256, 1><<<768, 256, 0, stream>>>(
        wkqv + (size_t)l * 3 * 512 * 256, xcl, biascat + l * 1536, l,
        k_tok, v_tok, q_tok, nullptr);
    const unsigned int* qt = (const unsigned int*)q_tok;
    const unsigned int* kt = (const unsigned int*)k_tok;
    const unsigned int* vt = (const unsigned int*)v_tok;
    unsigned int* op = (unsigned int*)opad;
    switch (l) {
      case 0: k_attn<0><<<1024, 256, 0, stream>>>(qt, kt, vt, op); break;
      case 1: k_attn<1><<<1024, 256, 0, stream>>>(qt, kt, vt, op); break;
      case 2: k_attn<2><<<1024, 256, 0, stream>>>(qt, kt, vt, op); break;
      default: k_attn<3><<<1024, 256, 0, stream>>>(qt, kt, vt, op); break;
    }
    k_gemm<1, 18, 4608, 512, 2><<<512, 256, 0, stream>>>(
        w1bf + (size_t)l * 256 * 4608, opad, nullptr, l,
        nullptr, nullptr, nullptr, p1);
    k_comb_stats<<<256, 512, 0, stream>>>((const unsigned int*)p1, ob1 + l * 256,
                                          bn_g + l * 256, bn_b + l * 256, stats);
    k_bn_relu_pad<<<dim3(32, 8), 512, 0, stream>>>((const unsigned int*)p1,
                                                   ob1 + l * 256, stats, h1pad);
    k_gemm<2, 9, 2304, 256, 2><<<512, 256, 0, stream>>>(
        w2bf + (size_t)l * 256 * 2304, h1pad, nullptr, l,
        nullptr, nullptr, nullptr, p1);
    k_comb2<<<dim3(32, 8), 512, 0, stream>>>((const unsigned int*)p1, ob2 + l * 256,
                                             gammas + l, (l == 3) ? 1 : 0, xacc, xcl);
  }
}